// Round 5
// baseline (578.973 us; speedup 1.0000x reference)
//
#include <hip/hip_runtime.h>

#define NSAMP 400000
#define ROWS_PER_BLK 64
#define NBLK1 6250      // 400000 / 64 exactly
#define NBLK_E 1563     // ceil(400000/256)

// ---- workspace layout (bytes) ----
// 0       : double acc[64]   [0..3]=gsum [4..15]=gz [16..39]=gzz [40]=loss1sum
//                            [41]=energy_sum [42]=lossPart [44]=energy ticket
//                            [46]=gmm ticket
// 512     : float  P[10]
// 1024    : float  Gm[256]   dec_w3 * dec_w3^T
// 2048    : float  gv[16]    dec_w3 * dec_b3
// 2112    : float  bb[1]     ||dec_b3||^2
// 4096    : float  Pp[41][6250]  per-block moment partials (1.03 MB)
// 2097152 : float4 zbuf[NSAMP]   (6.4 MB)

__device__ __forceinline__ float ftanh(float x) {
    float e = __expf(2.0f * x);
    return 1.0f - __fdividef(2.0f, e + 1.0f);
}

__device__ __forceinline__ void gl_lds16(const float* g, float* l) {
    __builtin_amdgcn_global_load_lds(
        (const __attribute__((address_space(1))) void*)(g),
        (__attribute__((address_space(3))) void*)(l), 16, 0, 0);
}

__global__ __launch_bounds__(256) void prep_kernel(const float* __restrict__ dw3,
                                                   const float* __restrict__ db3,
                                                   float* __restrict__ Gm,
                                                   float* __restrict__ gv,
                                                   float* __restrict__ bb) {
    int t = threadIdx.x;
    int a = t >> 4, b = t & 15;
    float s = 0.f;
    for (int j = 0; j < 128; ++j) s = fmaf(dw3[a * 128 + j], dw3[b * 128 + j], s);
    Gm[t] = s;
    if (t < 16) {
        float sg = 0.f;
        for (int j = 0; j < 128; ++j) sg = fmaf(dw3[t * 128 + j], db3[j], sg);
        gv[t] = sg;
    }
    if (t == 0) {
        float sv = 0.f;
        for (int j = 0; j < 128; ++j) sv = fmaf(db3[j], db3[j], sv);
        *bb = sv;
    }
}

// LDS: tile region = 32 DMA instrs x 260 floats (1040 B: 2 rows of 128 + 16 B pad)
//      = 8320 floats; partials region (reused, [slot][thread]) = 9*256 float4
//      = 9216 floats = 36864 B -> 4 blocks/CU.
__global__ __launch_bounds__(256) void pass1_kernel(
    const float* __restrict__ x1,
    const float* __restrict__ ew1, const float* __restrict__ eb1,
    const float* __restrict__ ew2, const float* __restrict__ eb2,
    const float* __restrict__ ew3, const float* __restrict__ eb3,
    const float* __restrict__ dw1, const float* __restrict__ db1,
    const float* __restrict__ dw2, const float* __restrict__ db2,
    const float* __restrict__ dw3, const float* __restrict__ db3,
    const float* __restrict__ tw1, const float* __restrict__ tb1,
    const float* __restrict__ tw2, const float* __restrict__ tb2,
    const float* __restrict__ Gm, const float* __restrict__ gv,
    const float* __restrict__ bbp,
    float* __restrict__ Pp, float4* __restrict__ zbuf) {
    __shared__ float lds[9216];

    int t = threadIdx.x;
    int w = t >> 6;          // wave id = column quarter
    int lane = t & 63;       // also row id for compute/tail
    int blk = blockIdx.x;
    size_t rowbase = (size_t)blk * ROWS_PER_BLK;

    // ---- one-shot DMA of the whole 64x128 tile, fully contiguous ----
    // instr i covers rows {2i, 2i+1}: lane l -> row 2i+(l>>5), col4 (l&31).
    // 1 KB contiguous global per instr; LDS base i*1040 B (wave-uniform).
#pragma unroll
    for (int k = 0; k < 8; ++k) {
        int i = w * 8 + k;
        int r = 2 * i + (lane >> 5);
        const float* src = x1 + (rowbase + r) * 128 + (lane & 31) * 4;
        gl_lds16(src, &lds[i * 260]);
    }
    __syncthreads();   // drains DMA (vmcnt) + barrier

    // ---- streamed split-K GEMV: row=lane, cols [w*32, w*32+32) in groups of 4
    // slot(r, j4) = (r>>1)*65 + (r&1)*32 + j4 ; start-bank quad ((r>>1)+j4)%8
    // -> dense 8 dwords/bank per b128 (free regime). Live set ~45 VGPRs: no spill.
    float u[16], v[16];
#pragma unroll
    for (int k = 0; k < 16; ++k) { u[k] = 0.f; v[k] = 0.f; }
    float s2 = 0.f, sb = 0.f;
    {
        int sbase = (lane >> 1) * 65 + (lane & 1) * 32 + w * 8;
        float4 cur4 = *(const float4*)&lds[sbase * 4];
#pragma unroll
        for (int m = 0; m < 8; ++m) {
            float4 nxt4 = cur4;
            if (m < 7) nxt4 = *(const float4*)&lds[(sbase + m + 1) * 4];
            int c = w * 32 + m * 4;
            float x0 = cur4.x, x1e = cur4.y, x2e = cur4.z, x3e = cur4.w;
            s2 = fmaf(x0, x0, s2); s2 = fmaf(x1e, x1e, s2);
            s2 = fmaf(x2e, x2e, s2); s2 = fmaf(x3e, x3e, s2);
            sb = fmaf(x0, db3[c + 0], sb); sb = fmaf(x1e, db3[c + 1], sb);
            sb = fmaf(x2e, db3[c + 2], sb); sb = fmaf(x3e, db3[c + 3], sb);
#pragma unroll
            for (int k = 0; k < 16; ++k) {
                float a2 = u[k];
                a2 = fmaf(x0,  ew1[(c + 0) * 16 + k], a2);
                a2 = fmaf(x1e, ew1[(c + 1) * 16 + k], a2);
                a2 = fmaf(x2e, ew1[(c + 2) * 16 + k], a2);
                a2 = fmaf(x3e, ew1[(c + 3) * 16 + k], a2);
                u[k] = a2;
            }
#pragma unroll
            for (int q = 0; q < 16; ++q) {
                float a2 = v[q];
                a2 = fmaf(x0,  dw3[q * 128 + c + 0], a2);
                a2 = fmaf(x1e, dw3[q * 128 + c + 1], a2);
                a2 = fmaf(x2e, dw3[q * 128 + c + 2], a2);
                a2 = fmaf(x3e, dw3[q * 128 + c + 3], a2);
                v[q] = a2;
            }
            cur4 = nxt4;
        }
    }

    // ---- write partials, [slot][thread] layout: stride-1 across lanes ----
    __syncthreads();   // everyone done reading tile (region reuse)
    *(float4*)&lds[(0 * 256 + t) * 4] = make_float4(u[0], u[1], u[2], u[3]);
    *(float4*)&lds[(1 * 256 + t) * 4] = make_float4(u[4], u[5], u[6], u[7]);
    *(float4*)&lds[(2 * 256 + t) * 4] = make_float4(u[8], u[9], u[10], u[11]);
    *(float4*)&lds[(3 * 256 + t) * 4] = make_float4(u[12], u[13], u[14], u[15]);
    *(float4*)&lds[(4 * 256 + t) * 4] = make_float4(v[0], v[1], v[2], v[3]);
    *(float4*)&lds[(5 * 256 + t) * 4] = make_float4(v[4], v[5], v[6], v[7]);
    *(float4*)&lds[(6 * 256 + t) * 4] = make_float4(v[8], v[9], v[10], v[11]);
    *(float4*)&lds[(7 * 256 + t) * 4] = make_float4(v[12], v[13], v[14], v[15]);
    *(float4*)&lds[(8 * 256 + t) * 4] = make_float4(s2, sb, 0.f, 0.f);
    __syncthreads();   // last barrier; waves 1..3 exit after this

    if (t >= 64) return;

    // ---- tail: lane r = t sums the 4 partials, runs the per-row MLP tail ----
    float U[16], V[16];
#pragma unroll
    for (int k = 0; k < 16; ++k) { U[k] = 0.f; V[k] = 0.f; }
    float S2 = 0.f, SB = 0.f;
#pragma unroll
    for (int p = 0; p < 4; ++p) {
        int col = p * 64 + t;
#pragma unroll
        for (int s = 0; s < 4; ++s) {
            float4 a4 = *(const float4*)&lds[((s)     * 256 + col) * 4];
            U[s * 4 + 0] += a4.x; U[s * 4 + 1] += a4.y;
            U[s * 4 + 2] += a4.z; U[s * 4 + 3] += a4.w;
            float4 b4 = *(const float4*)&lds[((s + 4) * 256 + col) * 4];
            V[s * 4 + 0] += b4.x; V[s * 4 + 1] += b4.y;
            V[s * 4 + 2] += b4.z; V[s * 4 + 3] += b4.w;
        }
        float4 s4 = *(const float4*)&lds[(8 * 256 + col) * 4];
        S2 += s4.x; SB += s4.y;
    }

    // encoder tail
    float h1[16];
#pragma unroll
    for (int k = 0; k < 16; ++k) h1[k] = ftanh(U[k] + eb1[k]);
    float h2[8];
#pragma unroll
    for (int m = 0; m < 8; ++m) {
        float a2 = eb2[m];
#pragma unroll
        for (int k = 0; k < 16; ++k) a2 = fmaf(h1[k], ew2[k * 8 + m], a2);
        h2[m] = ftanh(a2);
    }
    float a3 = eb3[0];
#pragma unroll
    for (int m = 0; m < 8; ++m) a3 = fmaf(h2[m], ew3[m], a3);
    float z1 = ftanh(a3);

    // decoder
    float d1[8];
#pragma unroll
    for (int p = 0; p < 8; ++p) d1[p] = ftanh(fmaf(z1, dw1[p], db1[p]));
    float d2[16];
#pragma unroll
    for (int q = 0; q < 16; ++q) {
        float a2 = db2[q];
#pragma unroll
        for (int p = 0; p < 8; ++p) a2 = fmaf(d1[p], dw2[p * 16 + q], a2);
        d2[q] = ftanh(a2);
    }

    // distances via Gram (global, wave-uniform -> scalar loads)
    float dot = SB;
#pragma unroll
    for (int q = 0; q < 16; ++q) dot = fmaf(d2[q], V[q], dot);
    float n2 = *bbp;
#pragma unroll
    for (int a = 0; a < 16; ++a) {
        float ra = 2.0f * gv[a];
#pragma unroll
        for (int b = 0; b < 16; ++b) ra = fmaf(Gm[a * 16 + b], d2[b], ra);
        n2 = fmaf(d2[a], ra, n2);
    }
    n2 = fmaxf(n2, 1e-20f);
    float euc2 = fmaxf(S2 - 2.0f * dot + n2, 0.f);
    float deuc = sqrtf(euc2);
    float dcos = dot * rsqrtf(S2 * n2);

    float zf[3] = {z1, dcos, deuc};

    // estimator
    float e1[8];
#pragma unroll
    for (int p = 0; p < 8; ++p) {
        float a2 = tb1[p];
        a2 = fmaf(zf[0], tw1[0 * 8 + p], a2);
        a2 = fmaf(zf[1], tw1[1 * 8 + p], a2);
        a2 = fmaf(zf[2], tw1[2 * 8 + p], a2);
        e1[p] = ftanh(a2);
    }
    float lg[4];
#pragma unroll
    for (int k = 0; k < 4; ++k) {
        float a2 = tb2[k];
#pragma unroll
        for (int p = 0; p < 8; ++p) a2 = fmaf(e1[p], tw2[p * 4 + k], a2);
        lg[k] = a2;
    }
    float mx = fmaxf(fmaxf(lg[0], lg[1]), fmaxf(lg[2], lg[3]));
    float ex[4]; float se = 0.f;
#pragma unroll
    for (int k = 0; k < 4; ++k) { ex[k] = __expf(lg[k] - mx); se += ex[k]; }
    float inv = __fdividef(1.0f, se);
    float gam[4];
#pragma unroll
    for (int k = 0; k < 4; ++k) gam[k] = ex[k] * inv;

    zbuf[rowbase + t] = make_float4(zf[0], zf[1], zf[2], 0.f);

    // wave-0 reduction of 41 moments -> per-block fp32 partials (no atomics)
#define RED(T, VAL) { float _v = (VAL);                                   \
        _v += __shfl_down(_v, 32); _v += __shfl_down(_v, 16);             \
        _v += __shfl_down(_v, 8);  _v += __shfl_down(_v, 4);              \
        _v += __shfl_down(_v, 2);  _v += __shfl_down(_v, 1);             \
        if (t == 0) Pp[(T) * NBLK1 + blk] = _v; }

#pragma unroll
    for (int k = 0; k < 4; ++k) RED(k, gam[k]);
#pragma unroll
    for (int k = 0; k < 4; ++k) {
#pragma unroll
        for (int d = 0; d < 3; ++d) RED(4 + k * 3 + d, gam[k] * zf[d]);
    }
#pragma unroll
    for (int k = 0; k < 4; ++k) {
        RED(16 + k * 6 + 0, gam[k] * zf[0] * zf[0]);
        RED(16 + k * 6 + 1, gam[k] * zf[0] * zf[1]);
        RED(16 + k * 6 + 2, gam[k] * zf[0] * zf[2]);
        RED(16 + k * 6 + 3, gam[k] * zf[1] * zf[1]);
        RED(16 + k * 6 + 4, gam[k] * zf[1] * zf[2]);
        RED(16 + k * 6 + 5, gam[k] * zf[2] * zf[2]);
    }
    RED(40, euc2);
#undef RED
}

// 41 blocks: block v reduces Pp[v][*] in f64; last block runs the GMM solve.
__global__ __launch_bounds__(256) void gmm_kernel(const float* __restrict__ Pp,
                                                  double* __restrict__ acc,
                                                  float* __restrict__ P) {
    int v = blockIdx.x;
    double s = 0.0;
    for (int i = threadIdx.x; i < NBLK1; i += 256) s += (double)Pp[v * NBLK1 + i];
    s += __shfl_down(s, 32); s += __shfl_down(s, 16); s += __shfl_down(s, 8);
    s += __shfl_down(s, 4);  s += __shfl_down(s, 2);  s += __shfl_down(s, 1);
    __shared__ double sd[4];
    if ((threadIdx.x & 63) == 0) sd[threadIdx.x >> 6] = s;
    __syncthreads();
    if (threadIdx.x != 0) return;
    double tot = sd[0] + sd[1] + sd[2] + sd[3];
    unsafeAtomicAdd(&acc[v], tot);          // device-coherent publish
    __threadfence();
    unsigned tk = atomicAdd((unsigned int*)(acc + 46), 1u);
    if (tk != 40) return;

    // last block: coherent read of all partial sums, then solve
    double a[41];
    for (int j = 0; j < 41; ++j) a[j] = unsafeAtomicAdd(&acc[j], 0.0);
    double M[6] = {0, 0, 0, 0, 0, 0}, bv[3] = {0, 0, 0}, A = 0.0, loss3 = 0.0;
    const double TWO_PI = 6.283185307179586;
    for (int k = 0; k < 4; ++k) {
        double g = a[k];
        double phi = g / (double)NSAMP;
        double mu0 = a[4 + k * 3 + 0] / g;
        double mu1 = a[4 + k * 3 + 1] / g;
        double mu2 = a[4 + k * 3 + 2] / g;
        double S00 = a[16 + k * 6 + 0] / g - mu0 * mu0;
        double S01 = a[16 + k * 6 + 1] / g - mu0 * mu1;
        double S02 = a[16 + k * 6 + 2] / g - mu0 * mu2;
        double S11 = a[16 + k * 6 + 3] / g - mu1 * mu1;
        double S12 = a[16 + k * 6 + 4] / g - mu1 * mu2;
        double S22 = a[16 + k * 6 + 5] / g - mu2 * mu2;
        double c00 = S11 * S22 - S12 * S12;
        double c01 = S02 * S12 - S01 * S22;
        double c02 = S01 * S12 - S02 * S11;
        double det = S00 * c00 + S01 * c01 + S02 * c02;
        double id = 1.0 / det;
        double I00 = c00 * id, I01 = c01 * id, I02 = c02 * id;
        double I11 = (S00 * S22 - S02 * S02) * id;
        double I12 = (S01 * S02 - S00 * S12) * id;
        double I22 = (S00 * S11 - S01 * S01) * id;
        M[0] += I00; M[1] += I01; M[2] += I02; M[3] += I11; M[4] += I12; M[5] += I22;
        double b0 = I00 * mu0 + I01 * mu1 + I02 * mu2;
        double b1 = I01 * mu0 + I11 * mu1 + I12 * mu2;
        double b2 = I02 * mu0 + I12 * mu1 + I22 * mu2;
        bv[0] += b0; bv[1] += b1; bv[2] += b2;
        double quad = mu0 * b0 + mu1 * b1 + mu2 * b2;
        A += -log(phi) + 0.5 * log(TWO_PI * TWO_PI * TWO_PI * det) + 0.5 * quad;
        loss3 += 1e-4 * (1.0 / S00 + 1.0 / S11 + 1.0 / S22);
    }
    P[0] = (float)M[0]; P[1] = (float)M[1]; P[2] = (float)M[2];
    P[3] = (float)M[3]; P[4] = (float)M[4]; P[5] = (float)M[5];
    P[6] = (float)bv[0]; P[7] = (float)bv[1]; P[8] = (float)bv[2];
    P[9] = (float)A;
    unsafeAtomicAdd(&acc[42], a[40] / (double)NSAMP + loss3);  // loss1 + loss3
}

__global__ __launch_bounds__(256) void energy_kernel(const float4* __restrict__ zbuf,
                                                     const float* __restrict__ P,
                                                     double* __restrict__ acc,
                                                     float* __restrict__ out) {
    int i = blockIdx.x * 256 + threadIdx.x;
    float e = 0.f;
    if (i < NSAMP) {
        float4 z4 = zbuf[i];
        float z0 = z4.x, z1 = z4.y, z2 = z4.z;
        float q = P[0] * z0 * z0 + P[3] * z1 * z1 + P[5] * z2 * z2
                + 2.f * (P[1] * z0 * z1 + P[2] * z0 * z2 + P[4] * z1 * z2);
        e = P[9] + 0.5f * q - (P[6] * z0 + P[7] * z1 + P[8] * z2);
        out[i] = e;
    }
    float s = e;
    s += __shfl_down(s, 32); s += __shfl_down(s, 16); s += __shfl_down(s, 8);
    s += __shfl_down(s, 4);  s += __shfl_down(s, 2);  s += __shfl_down(s, 1);
    __shared__ float sE[4];
    if ((threadIdx.x & 63) == 0) sE[threadIdx.x >> 6] = s;
    __syncthreads();
    if (threadIdx.x == 0) {
        double t = (double)sE[0] + (double)sE[1] + (double)sE[2] + (double)sE[3];
        unsafeAtomicAdd(&acc[41], t);
        __threadfence();
        unsigned tk = atomicAdd((unsigned int*)(acc + 44), 1u);
        if (tk == NBLK_E - 1) {
            double esum = unsafeAtomicAdd(&acc[41], 0.0);
            double lpart = unsafeAtomicAdd(&acc[42], 0.0);
            out[NSAMP] = (float)(lpart + 0.01 * esum / (double)NSAMP);
        }
    }
}

extern "C" void kernel_launch(void* const* d_in, const int* in_sizes, int n_in,
                              void* d_out, int out_size, void* d_ws, size_t ws_size,
                              hipStream_t stream) {
    const float* x1  = (const float*)d_in[0];
    const float* ew1 = (const float*)d_in[1];
    const float* eb1 = (const float*)d_in[2];
    const float* ew2 = (const float*)d_in[3];
    const float* eb2 = (const float*)d_in[4];
    const float* ew3 = (const float*)d_in[5];
    const float* eb3 = (const float*)d_in[6];
    const float* dw1 = (const float*)d_in[7];
    const float* db1 = (const float*)d_in[8];
    const float* dw2 = (const float*)d_in[9];
    const float* db2 = (const float*)d_in[10];
    const float* dw3 = (const float*)d_in[11];
    const float* db3 = (const float*)d_in[12];
    const float* tw1 = (const float*)d_in[13];
    const float* tb1 = (const float*)d_in[14];
    const float* tw2 = (const float*)d_in[15];
    const float* tb2 = (const float*)d_in[16];
    float* out = (float*)d_out;
    char* ws = (char*)d_ws;
    double* acc = (double*)ws;
    float* P    = (float*)(ws + 512);
    float* Gm   = (float*)(ws + 1024);
    float* gv   = (float*)(ws + 2048);
    float* bb   = (float*)(ws + 2112);
    float* Pp   = (float*)(ws + 4096);
    float4* zb  = (float4*)(ws + 2097152);

    hipMemsetAsync(d_ws, 0, 512, stream);
    prep_kernel<<<1, 256, 0, stream>>>(dw3, db3, Gm, gv, bb);
    pass1_kernel<<<NBLK1, 256, 0, stream>>>(x1, ew1, eb1, ew2, eb2, ew3, eb3,
                                            dw1, db1, dw2, db2, dw3, db3,
                                            tw1, tb1, tw2, tb2, Gm, gv, bb, Pp, zb);
    gmm_kernel<<<41, 256, 0, stream>>>(Pp, acc, P);
    energy_kernel<<<NBLK_E, 256, 0, stream>>>(zb, P, acc, out);
}

// Round 6
// 568.916 us; speedup vs baseline: 1.0177x; 1.0177x over previous
//
#include <hip/hip_runtime.h>

#define NSAMP 400000
#define NBLKP 1563      // pass1/energy blocks: ceil(400000/256)

// ---- workspace layout (bytes) ----
// 0       : double acc[64]   [0..40]=moments+loss1 [41]=energy_sum [42]=lossPart
//                            [44]=energy ticket [46]=gmm ticket
// 512     : float  P[10]
// 1024    : float  Gm[256]   dec_w3 * dec_w3^T
// 2048    : float  gv[16]    dec_w3 * dec_b3
// 2112    : float  bb[1]     ||dec_b3||^2
// 4096    : float  Pp[41][NBLKP]  per-block moment partials (~256 KB)
// 2097152 : float4 zbuf[NSAMP]    (6.4 MB)

__device__ __forceinline__ float ftanh(float x) {
    float e = __expf(2.0f * x);
    return 1.0f - __fdividef(2.0f, e + 1.0f);
}

__global__ __launch_bounds__(256) void prep_kernel(const float* __restrict__ dw3,
                                                   const float* __restrict__ db3,
                                                   float* __restrict__ Gm,
                                                   float* __restrict__ gv,
                                                   float* __restrict__ bb) {
    int t = threadIdx.x;
    int a = t >> 4, b = t & 15;
    float s = 0.f;
    for (int j = 0; j < 128; ++j) s = fmaf(dw3[a * 128 + j], dw3[b * 128 + j], s);
    Gm[t] = s;
    if (t < 16) {
        float sg = 0.f;
        for (int j = 0; j < 128; ++j) sg = fmaf(dw3[t * 128 + j], db3[j], sg);
        gv[t] = sg;
    }
    if (t == 0) {
        float sv = 0.f;
        for (int j = 0; j < 128; ++j) sv = fmaf(db3[j], db3[j], sv);
        *bb = sv;
    }
}

// Double-buffered 256x16 chunk tiles, row stride 17 floats.
// No value lives across a barrier -> no spill by construction.
#define TS 17
#define CHUNK_LDS (256 * TS)

__global__ __launch_bounds__(256) void pass1_kernel(
    const float* __restrict__ x1,
    const float* __restrict__ ew1, const float* __restrict__ eb1,
    const float* __restrict__ ew2, const float* __restrict__ eb2,
    const float* __restrict__ ew3, const float* __restrict__ eb3,
    const float* __restrict__ dw1, const float* __restrict__ db1,
    const float* __restrict__ dw2, const float* __restrict__ db2,
    const float* __restrict__ dw3, const float* __restrict__ db3,
    const float* __restrict__ tw1, const float* __restrict__ tb1,
    const float* __restrict__ tw2, const float* __restrict__ tb2,
    const float* __restrict__ Gm, const float* __restrict__ gv,
    const float* __restrict__ bbp,
    float* __restrict__ Pp, float4* __restrict__ zbuf) {
    __shared__ float bufA[CHUNK_LDS];
    __shared__ float bufB[CHUNK_LDS];
    __shared__ float sPart[4][41];

    int t = threadIdx.x;
    int i = blockIdx.x * 256 + t;
    int base = blockIdx.x * 256;
    bool active = (i < NSAMP);

    // staging geometry: float4 id f = t + 256*s -> row f>>2, col4 f&3
    int srow4[4], sc4[4];
#pragma unroll
    for (int s = 0; s < 4; ++s) {
        int f = t + 256 * s;
        srow4[s] = f >> 2;
        sc4[s] = f & 3;
    }

    // ---- stage chunk 0 (load -> immediate LDS write, same scope) ----
    {
#pragma unroll
        for (int s = 0; s < 4; ++s) {
            int grow = base + srow4[s];
            if (grow >= NSAMP) grow = NSAMP - 1;
            float4 g = *(const float4*)(x1 + (size_t)grow * 128 + sc4[s] * 4);
            *(float4*)&bufA[srow4[s] * TS + sc4[s] * 4] = g;
        }
    }
    __syncthreads();

    float u[16], v[16];
#pragma unroll
    for (int k = 0; k < 16; ++k) { u[k] = 0.f; v[k] = 0.f; }
    float s2 = 0.f, sb = 0.f;

#pragma unroll 1
    for (int blk = 0; blk < 8; ++blk) {
        float* cur = (blk & 1) ? bufB : bufA;
        float* nxt = (blk & 1) ? bufA : bufB;

        // issue next chunk's global loads (consumed BEFORE the barrier below)
        float4 g[4];
        if (blk < 7) {
#pragma unroll
            for (int s = 0; s < 4; ++s) {
                int grow = base + srow4[s];
                if (grow >= NSAMP) grow = NSAMP - 1;
                g[s] = *(const float4*)(x1 + (size_t)grow * 128 + (blk + 1) * 16 + sc4[s] * 4);
            }
        }

        // my row from LDS: 4x ds_read_b128, stride-17 rows (4-way alias, ~free)
        float xe[16];
        {
            const float* rb = cur + t * TS;
#pragma unroll
            for (int c = 0; c < 4; ++c) {
                float4 a4 = *(const float4*)(rb + c * 4);
                xe[c * 4 + 0] = a4.x; xe[c * 4 + 1] = a4.y;
                xe[c * 4 + 2] = a4.z; xe[c * 4 + 3] = a4.w;
            }
        }

        // FMAs (~544 cyc/wave) cover the in-flight loads' latency
        int j0 = blk * 16;
#pragma unroll
        for (int e = 0; e < 16; ++e) {
            float x = xe[e];
            s2 = fmaf(x, x, s2);
            sb = fmaf(x, db3[j0 + e], sb);
#pragma unroll
            for (int k = 0; k < 16; ++k) u[k] = fmaf(x, ew1[(j0 + e) * 16 + k], u[k]);
        }
#pragma unroll
        for (int q = 0; q < 16; ++q) {
            float a2 = v[q];
#pragma unroll
            for (int e = 0; e < 16; ++e) a2 = fmaf(xe[e], dw3[q * 128 + j0 + e], a2);
            v[q] = a2;
        }

        // drain loads into the other buffer (no cross-barrier liveness)
        if (blk < 7) {
#pragma unroll
            for (int s = 0; s < 4; ++s)
                *(float4*)&nxt[srow4[s] * TS + sc4[s] * 4] = g[s];
        }
        __syncthreads();
    }

    // encoder tail
    float h1[16];
#pragma unroll
    for (int k = 0; k < 16; ++k) h1[k] = ftanh(u[k] + eb1[k]);
    float h2[8];
#pragma unroll
    for (int m = 0; m < 8; ++m) {
        float a2 = eb2[m];
#pragma unroll
        for (int k = 0; k < 16; ++k) a2 = fmaf(h1[k], ew2[k * 8 + m], a2);
        h2[m] = ftanh(a2);
    }
    float a3 = eb3[0];
#pragma unroll
    for (int m = 0; m < 8; ++m) a3 = fmaf(h2[m], ew3[m], a3);
    float z1 = ftanh(a3);

    // decoder (x2 never materialized)
    float d1[8];
#pragma unroll
    for (int p = 0; p < 8; ++p) d1[p] = ftanh(fmaf(z1, dw1[p], db1[p]));
    float d2[16];
#pragma unroll
    for (int q = 0; q < 16; ++q) {
        float a2 = db2[q];
#pragma unroll
        for (int p = 0; p < 8; ++p) a2 = fmaf(d1[p], dw2[p * 16 + q], a2);
        d2[q] = ftanh(a2);
    }

    // distances via precomputed Gram (wave-uniform -> scalar loads)
    float dot = sb;
#pragma unroll
    for (int q = 0; q < 16; ++q) dot = fmaf(d2[q], v[q], dot);
    float n2 = *bbp;
#pragma unroll
    for (int a = 0; a < 16; ++a) {
        float ra = 2.0f * gv[a];
#pragma unroll
        for (int b = 0; b < 16; ++b) ra = fmaf(Gm[a * 16 + b], d2[b], ra);
        n2 = fmaf(d2[a], ra, n2);
    }
    n2 = fmaxf(n2, 1e-20f);
    float euc2 = fmaxf(s2 - 2.0f * dot + n2, 0.f);
    float deuc = sqrtf(euc2);
    float dcos = dot * rsqrtf(s2 * n2);

    float zf[3] = {z1, dcos, deuc};

    // estimator
    float e1[8];
#pragma unroll
    for (int p = 0; p < 8; ++p) {
        float a2 = tb1[p];
        a2 = fmaf(zf[0], tw1[0 * 8 + p], a2);
        a2 = fmaf(zf[1], tw1[1 * 8 + p], a2);
        a2 = fmaf(zf[2], tw1[2 * 8 + p], a2);
        e1[p] = ftanh(a2);
    }
    float lg[4];
#pragma unroll
    for (int k = 0; k < 4; ++k) {
        float a2 = tb2[k];
#pragma unroll
        for (int p = 0; p < 8; ++p) a2 = fmaf(e1[p], tw2[p * 4 + k], a2);
        lg[k] = a2;
    }
    float mx = fmaxf(fmaxf(lg[0], lg[1]), fmaxf(lg[2], lg[3]));
    float ex[4]; float se = 0.f;
#pragma unroll
    for (int k = 0; k < 4; ++k) { ex[k] = __expf(lg[k] - mx); se += ex[k]; }
    float inv = __fdividef(1.0f, se);
    float gam[4];
#pragma unroll
    for (int k = 0; k < 4; ++k) gam[k] = ex[k] * inv;

    if (active) zbuf[i] = make_float4(zf[0], zf[1], zf[2], 0.f);
    if (!active) { gam[0] = gam[1] = gam[2] = gam[3] = 0.f; euc2 = 0.f; }

    // block reduction of 41 moments -> fp32 partials in Pp (no global atomics)
    int lane = t & 63;
    int wid = t >> 6;

#define RED(T, VAL) { float _v = (VAL);                                   \
        _v += __shfl_down(_v, 32); _v += __shfl_down(_v, 16);             \
        _v += __shfl_down(_v, 8);  _v += __shfl_down(_v, 4);              \
        _v += __shfl_down(_v, 2);  _v += __shfl_down(_v, 1);              \
        if (lane == 0) sPart[wid][T] = _v; }

#pragma unroll
    for (int k = 0; k < 4; ++k) RED(k, gam[k]);
#pragma unroll
    for (int k = 0; k < 4; ++k) {
#pragma unroll
        for (int d = 0; d < 3; ++d) RED(4 + k * 3 + d, gam[k] * zf[d]);
    }
#pragma unroll
    for (int k = 0; k < 4; ++k) {
        RED(16 + k * 6 + 0, gam[k] * zf[0] * zf[0]);
        RED(16 + k * 6 + 1, gam[k] * zf[0] * zf[1]);
        RED(16 + k * 6 + 2, gam[k] * zf[0] * zf[2]);
        RED(16 + k * 6 + 3, gam[k] * zf[1] * zf[1]);
        RED(16 + k * 6 + 4, gam[k] * zf[1] * zf[2]);
        RED(16 + k * 6 + 5, gam[k] * zf[2] * zf[2]);
    }
    RED(40, euc2);
#undef RED

    __syncthreads();
    if (t < 41) {
        float s = sPart[0][t] + sPart[1][t] + sPart[2][t] + sPart[3][t];
        Pp[t * NBLKP + blockIdx.x] = s;
    }
}

// 41 blocks: block v reduces Pp[v][*] in f64; last block runs the GMM solve.
__global__ __launch_bounds__(256) void gmm_kernel(const float* __restrict__ Pp,
                                                  double* __restrict__ acc,
                                                  float* __restrict__ P) {
    int v = blockIdx.x;
    double s = 0.0;
    for (int i = threadIdx.x; i < NBLKP; i += 256) s += (double)Pp[v * NBLKP + i];
    s += __shfl_down(s, 32); s += __shfl_down(s, 16); s += __shfl_down(s, 8);
    s += __shfl_down(s, 4);  s += __shfl_down(s, 2);  s += __shfl_down(s, 1);
    __shared__ double sd[4];
    if ((threadIdx.x & 63) == 0) sd[threadIdx.x >> 6] = s;
    __syncthreads();
    if (threadIdx.x != 0) return;
    double tot = sd[0] + sd[1] + sd[2] + sd[3];
    unsafeAtomicAdd(&acc[v], tot);          // device-coherent publish
    __threadfence();
    unsigned tk = atomicAdd((unsigned int*)(acc + 46), 1u);
    if (tk != 40) return;

    // last block: coherent read of all partial sums, then solve
    double a[41];
    for (int j = 0; j < 41; ++j) a[j] = unsafeAtomicAdd(&acc[j], 0.0);
    double M[6] = {0, 0, 0, 0, 0, 0}, bv[3] = {0, 0, 0}, A = 0.0, loss3 = 0.0;
    const double TWO_PI = 6.283185307179586;
    for (int k = 0; k < 4; ++k) {
        double g = a[k];
        double phi = g / (double)NSAMP;
        double mu0 = a[4 + k * 3 + 0] / g;
        double mu1 = a[4 + k * 3 + 1] / g;
        double mu2 = a[4 + k * 3 + 2] / g;
        double S00 = a[16 + k * 6 + 0] / g - mu0 * mu0;
        double S01 = a[16 + k * 6 + 1] / g - mu0 * mu1;
        double S02 = a[16 + k * 6 + 2] / g - mu0 * mu2;
        double S11 = a[16 + k * 6 + 3] / g - mu1 * mu1;
        double S12 = a[16 + k * 6 + 4] / g - mu1 * mu2;
        double S22 = a[16 + k * 6 + 5] / g - mu2 * mu2;
        double c00 = S11 * S22 - S12 * S12;
        double c01 = S02 * S12 - S01 * S22;
        double c02 = S01 * S12 - S02 * S11;
        double det = S00 * c00 + S01 * c01 + S02 * c02;
        double id = 1.0 / det;
        double I00 = c00 * id, I01 = c01 * id, I02 = c02 * id;
        double I11 = (S00 * S22 - S02 * S02) * id;
        double I12 = (S01 * S02 - S00 * S12) * id;
        double I22 = (S00 * S11 - S01 * S01) * id;
        M[0] += I00; M[1] += I01; M[2] += I02; M[3] += I11; M[4] += I12; M[5] += I22;
        double b0 = I00 * mu0 + I01 * mu1 + I02 * mu2;
        double b1 = I01 * mu0 + I11 * mu1 + I12 * mu2;
        double b2 = I02 * mu0 + I12 * mu1 + I22 * mu2;
        bv[0] += b0; bv[1] += b1; bv[2] += b2;
        double quad = mu0 * b0 + mu1 * b1 + mu2 * b2;
        A += -log(phi) + 0.5 * log(TWO_PI * TWO_PI * TWO_PI * det) + 0.5 * quad;
        loss3 += 1e-4 * (1.0 / S00 + 1.0 / S11 + 1.0 / S22);
    }
    P[0] = (float)M[0]; P[1] = (float)M[1]; P[2] = (float)M[2];
    P[3] = (float)M[3]; P[4] = (float)M[4]; P[5] = (float)M[5];
    P[6] = (float)bv[0]; P[7] = (float)bv[1]; P[8] = (float)bv[2];
    P[9] = (float)A;
    unsafeAtomicAdd(&acc[42], a[40] / (double)NSAMP + loss3);  // loss1 + loss3
}

__global__ __launch_bounds__(256) void energy_kernel(const float4* __restrict__ zbuf,
                                                     const float* __restrict__ P,
                                                     double* __restrict__ acc,
                                                     float* __restrict__ out) {
    int i = blockIdx.x * 256 + threadIdx.x;
    float e = 0.f;
    if (i < NSAMP) {
        float4 z4 = zbuf[i];
        float z0 = z4.x, z1 = z4.y, z2 = z4.z;
        float q = P[0] * z0 * z0 + P[3] * z1 * z1 + P[5] * z2 * z2
                + 2.f * (P[1] * z0 * z1 + P[2] * z0 * z2 + P[4] * z1 * z2);
        e = P[9] + 0.5f * q - (P[6] * z0 + P[7] * z1 + P[8] * z2);
        out[i] = e;
    }
    float s = e;
    s += __shfl_down(s, 32); s += __shfl_down(s, 16); s += __shfl_down(s, 8);
    s += __shfl_down(s, 4);  s += __shfl_down(s, 2);  s += __shfl_down(s, 1);
    __shared__ float sE[4];
    if ((threadIdx.x & 63) == 0) sE[threadIdx.x >> 6] = s;
    __syncthreads();
    if (threadIdx.x == 0) {
        double t = (double)sE[0] + (double)sE[1] + (double)sE[2] + (double)sE[3];
        unsafeAtomicAdd(&acc[41], t);
        __threadfence();
        unsigned tk = atomicAdd((unsigned int*)(acc + 44), 1u);
        if (tk == NBLKP - 1) {
            double esum = unsafeAtomicAdd(&acc[41], 0.0);
            double lpart = unsafeAtomicAdd(&acc[42], 0.0);
            out[NSAMP] = (float)(lpart + 0.01 * esum / (double)NSAMP);
        }
    }
}

extern "C" void kernel_launch(void* const* d_in, const int* in_sizes, int n_in,
                              void* d_out, int out_size, void* d_ws, size_t ws_size,
                              hipStream_t stream) {
    const float* x1  = (const float*)d_in[0];
    const float* ew1 = (const float*)d_in[1];
    const float* eb1 = (const float*)d_in[2];
    const float* ew2 = (const float*)d_in[3];
    const float* eb2 = (const float*)d_in[4];
    const float* ew3 = (const float*)d_in[5];
    const float* eb3 = (const float*)d_in[6];
    const float* dw1 = (const float*)d_in[7];
    const float* db1 = (const float*)d_in[8];
    const float* dw2 = (const float*)d_in[9];
    const float* db2 = (const float*)d_in[10];
    const float* dw3 = (const float*)d_in[11];
    const float* db3 = (const float*)d_in[12];
    const float* tw1 = (const float*)d_in[13];
    const float* tb1 = (const float*)d_in[14];
    const float* tw2 = (const float*)d_in[15];
    const float* tb2 = (const float*)d_in[16];
    float* out = (float*)d_out;
    char* ws = (char*)d_ws;
    double* acc = (double*)ws;
    float* P    = (float*)(ws + 512);
    float* Gm   = (float*)(ws + 1024);
    float* gv   = (float*)(ws + 2048);
    float* bb   = (float*)(ws + 2112);
    float* Pp   = (float*)(ws + 4096);
    float4* zb  = (float4*)(ws + 2097152);

    hipMemsetAsync(d_ws, 0, 512, stream);
    prep_kernel<<<1, 256, 0, stream>>>(dw3, db3, Gm, gv, bb);
    pass1_kernel<<<NBLKP, 256, 0, stream>>>(x1, ew1, eb1, ew2, eb2, ew3, eb3,
                                            dw1, db1, dw2, db2, dw3, db3,
                                            tw1, tb1, tw2, tb2, Gm, gv, bb, Pp, zb);
    gmm_kernel<<<41, 256, 0, stream>>>(Pp, acc, P);
    energy_kernel<<<NBLKP, 256, 0, stream>>>(zb, P, acc, out);
}